// Round 2
// baseline (745.468 us; speedup 1.0000x reference)
//
#include <hip/hip_runtime.h>
#include <hip/hip_bf16.h>

// MultiHeadAttentionBlock: B=2, S=4096, D=512, H=8, DK=64.
// fp32 in/out (per reference dtype), bf16 MFMA compute, fp32 accumulation.
// Pipeline: 3x proj GEMM (Q,K head-split; V transposed) -> flash attention -> out proj.

typedef __bf16 bf16_t;
typedef __bf16 bf16x8 __attribute__((ext_vector_type(8)));
typedef float f32x4 __attribute__((ext_vector_type(4)));

#define S_LEN 4096
#define NH 8
#define DK 64
#define DMODEL 512
#define NB 2

// Load 8 contiguous elements as a bf16x8 MFMA fragment.
__device__ inline bf16x8 frag8(const bf16_t* p) {
  return *reinterpret_cast<const bf16x8*>(p);
}
__device__ inline bf16x8 frag8(const float* p) {
  f32x4 a = *reinterpret_cast<const f32x4*>(p);
  f32x4 b = *reinterpret_cast<const f32x4*>(p + 4);
  bf16x8 r;
#pragma unroll
  for (int j = 0; j < 4; ++j) { r[j] = (__bf16)a[j]; r[j + 4] = (__bf16)b[j]; }
  return r;
}

// ---------------------------------------------------------------------------
// GEMM: out[m][n] = sum_k X[m][k] * W[n][k] + bias[n]
// M = 8192 (B*S), N = 512, K = 512. Tile 64x64 per block, wave -> 16(m) x 64(n).
// MFMA 16x16x32 bf16. A-frag: row = lane&15, k = (lane>>4)*8 + j (contiguous 16B).
// C/D: row = (lane>>4)*4 + reg, col = lane&15  [guide §3, m89/m91 verified].
// mode 0: out [B*H][S][DK] (head-split); mode 2: [B*H][DK][S] (transposed, for V);
// mode 1: plain [m][n].
// ---------------------------------------------------------------------------
template <typename TA, typename TB, typename TO>
__global__ __launch_bounds__(256) void gemm_proj(
    const TA* __restrict__ X, const TB* __restrict__ W,
    const float* __restrict__ bias, TO* __restrict__ out, int mode)
{
  const int mtile = blockIdx.x * 64;
  const int ntile = blockIdx.y * 64;
  const int wave = threadIdx.x >> 6;
  const int lane = threadIdx.x & 63;
  const int l16 = lane & 15;
  const int g = lane >> 4;
  const int m0 = mtile + wave * 16;

  f32x4 acc[4];
#pragma unroll
  for (int nb = 0; nb < 4; ++nb) acc[nb] = (f32x4){0.f, 0.f, 0.f, 0.f};

  const TA* xrow = X + (size_t)(m0 + l16) * DMODEL + g * 8;
  const TB* wbase = W + (size_t)(ntile + l16) * DMODEL + g * 8;

#pragma unroll 4
  for (int k = 0; k < DMODEL; k += 32) {
    bf16x8 af = frag8(xrow + k);
#pragma unroll
    for (int nb = 0; nb < 4; ++nb) {
      bf16x8 bfr = frag8(wbase + (size_t)nb * 16 * DMODEL + k);
      acc[nb] = __builtin_amdgcn_mfma_f32_16x16x32_bf16(af, bfr, acc[nb], 0, 0, 0);
    }
  }

#pragma unroll
  for (int nb = 0; nb < 4; ++nb) {
    const int n = ntile + nb * 16 + l16;
    const float bv = bias[n];
#pragma unroll
    for (int r = 0; r < 4; ++r) {
      const int m = m0 + g * 4 + r;
      float vv = acc[nb][r] + bv;
      size_t addr;
      if (mode == 0) {            // head-split [b*H+h][s][dk]
        int b = m >> 12, s = m & (S_LEN - 1);
        int h = n >> 6, d = n & 63;
        addr = (((size_t)(b * NH + h) * S_LEN) + s) * DK + d;
      } else if (mode == 2) {     // V transposed [b*H+h][dk][s]
        int b = m >> 12, s = m & (S_LEN - 1);
        int h = n >> 6, d = n & 63;
        addr = (((size_t)(b * NH + h) * DK) + d) * S_LEN + s;
      } else {                    // plain [m][n]
        addr = (size_t)m * DMODEL + n;
      }
      out[addr] = (TO)vv;
    }
  }
}

// ---------------------------------------------------------------------------
// Flash attention. Grid: (S/64, B*H). Block 256 = 4 waves; each wave owns 16 q-rows.
// KV tile = 32. Scores = (Q*0.125)·K^T via MFMA; online softmax (row stats in the
// 16-lane group owning that row); P bounced through per-wave LDS to A-frag layout;
// PV uses V^T (d-major) so B-frag loads are contiguous.
// ---------------------------------------------------------------------------
__global__ __launch_bounds__(256) void attn_kernel(
    const bf16_t* __restrict__ Qh, const bf16_t* __restrict__ Kh,
    const bf16_t* __restrict__ Vt, bf16_t* __restrict__ ctx)
{
  const int bh = blockIdx.y;                 // b*H + h
  const int b = bh >> 3, h = bh & 7;
  const int qbase = blockIdx.x * 64;
  const int wave = threadIdx.x >> 6;
  const int lane = threadIdx.x & 63;
  const int l16 = lane & 15;
  const int g = lane >> 4;                   // 0..3

  const bf16_t* Qp = Qh + (size_t)bh * S_LEN * DK;
  const bf16_t* Kp = Kh + (size_t)bh * S_LEN * DK;
  const bf16_t* Vp = Vt + (size_t)bh * DK * S_LEN;

  const int qrow0 = qbase + wave * 16;

  // Q fragments (2 k-steps of 32), pre-scaled by 1/sqrt(DK)=0.125 (exact in bf16)
  bf16x8 qf[2];
#pragma unroll
  for (int ks = 0; ks < 2; ++ks) {
    bf16x8 t = *reinterpret_cast<const bf16x8*>(
        Qp + (size_t)(qrow0 + l16) * DK + ks * 32 + g * 8);
#pragma unroll
    for (int j = 0; j < 8; ++j) t[j] = (__bf16)((float)t[j] * 0.125f);
    qf[ks] = t;
  }

  f32x4 o[4];
#pragma unroll
  for (int db = 0; db < 4; ++db) o[db] = (f32x4){0.f, 0.f, 0.f, 0.f};
  float m_run[4], l_run[4];
#pragma unroll
  for (int r = 0; r < 4; ++r) { m_run[r] = -1e30f; l_run[r] = 0.f; }

  __shared__ bf16_t pshare[4][16][32];       // per-wave P tile

  for (int kv = 0; kv < S_LEN; kv += 32) {
    // ---- scores: 16 q-rows x 32 kv-cols ----
    f32x4 sc[2];
#pragma unroll
    for (int nb = 0; nb < 2; ++nb) {
      f32x4 a = (f32x4){0.f, 0.f, 0.f, 0.f};
#pragma unroll
      for (int ks = 0; ks < 2; ++ks) {
        bf16x8 kf = *reinterpret_cast<const bf16x8*>(
            Kp + (size_t)(kv + nb * 16 + l16) * DK + ks * 32 + g * 8);
        a = __builtin_amdgcn_mfma_f32_16x16x32_bf16(qf[ks], kf, a, 0, 0, 0);
      }
      sc[nb] = a;
    }

    // ---- online softmax (row = g*4+r, shared by the 16 lanes of group g) ----
#pragma unroll
    for (int r = 0; r < 4; ++r) {
      float vmax = fmaxf(sc[0][r], sc[1][r]);
      vmax = fmaxf(vmax, __shfl_xor(vmax, 1));
      vmax = fmaxf(vmax, __shfl_xor(vmax, 2));
      vmax = fmaxf(vmax, __shfl_xor(vmax, 4));
      vmax = fmaxf(vmax, __shfl_xor(vmax, 8));
      const float mnew = fmaxf(m_run[r], vmax);
      const float alpha = __expf(m_run[r] - mnew);
      const float p0 = __expf(sc[0][r] - mnew);
      const float p1 = __expf(sc[1][r] - mnew);
      float psum = p0 + p1;
      psum += __shfl_xor(psum, 1);
      psum += __shfl_xor(psum, 2);
      psum += __shfl_xor(psum, 4);
      psum += __shfl_xor(psum, 8);
      l_run[r] = l_run[r] * alpha + psum;
      m_run[r] = mnew;
#pragma unroll
      for (int db = 0; db < 4; ++db) o[db][r] *= alpha;
      pshare[wave][g * 4 + r][l16] = (__bf16)p0;
      pshare[wave][g * 4 + r][16 + l16] = (__bf16)p1;
    }
    __syncthreads();

    // ---- PV: P (16x32) x V (32x64) ----
    bf16x8 pf = *reinterpret_cast<const bf16x8*>(&pshare[wave][l16][g * 8]);
#pragma unroll
    for (int db = 0; db < 4; ++db) {
      bf16x8 vf = *reinterpret_cast<const bf16x8*>(
          Vp + (size_t)(db * 16 + l16) * S_LEN + kv + g * 8);
      o[db] = __builtin_amdgcn_mfma_f32_16x16x32_bf16(pf, vf, o[db], 0, 0, 0);
    }
    __syncthreads();
  }

  // ---- epilogue: O / l -> ctx[b][s][h][dk] (bf16) ----
#pragma unroll
  for (int db = 0; db < 4; ++db) {
#pragma unroll
    for (int r = 0; r < 4; ++r) {
      const int row = qrow0 + g * 4 + r;
      const int col = db * 16 + l16;
      const float vv = o[db][r] / l_run[r];
      ctx[(((size_t)(b * S_LEN + row)) * NH + h) * DK + col] = (bf16_t)vv;
    }
  }
}

// ---------------------------------------------------------------------------
extern "C" void kernel_launch(void* const* d_in, const int* in_sizes, int n_in,
                              void* d_out, int out_size, void* d_ws, size_t ws_size,
                              hipStream_t stream)
{
  const float* q   = (const float*)d_in[0];
  const float* k   = (const float*)d_in[1];
  const float* v   = (const float*)d_in[2];
  const float* w_q = (const float*)d_in[3];
  const float* b_q = (const float*)d_in[4];
  const float* w_k = (const float*)d_in[5];
  const float* b_k = (const float*)d_in[6];
  const float* w_v = (const float*)d_in[7];
  const float* b_v = (const float*)d_in[8];
  const float* w_o = (const float*)d_in[9];
  const float* b_o = (const float*)d_in[10];
  float* out = (float*)d_out;

  char* ws = (char*)d_ws;
  const size_t sz = (size_t)NB * NH * S_LEN * DK * sizeof(bf16_t);  // 8 MiB each
  bf16_t* Qh  = (bf16_t*)(ws);
  bf16_t* Kh  = (bf16_t*)(ws + sz);
  bf16_t* Vt  = (bf16_t*)(ws + 2 * sz);
  bf16_t* ctx = (bf16_t*)(ws + 3 * sz);

  dim3 gg(128, 8), bb(256);
  gemm_proj<float, float, bf16_t><<<gg, bb, 0, stream>>>(q, w_q, b_q, Qh, 0);
  gemm_proj<float, float, bf16_t><<<gg, bb, 0, stream>>>(k, w_k, b_k, Kh, 0);
  gemm_proj<float, float, bf16_t><<<gg, bb, 0, stream>>>(v, w_v, b_v, Vt, 2);
  attn_kernel<<<dim3(S_LEN / 64, NB * NH), bb, 0, stream>>>(Qh, Kh, Vt, ctx);
  gemm_proj<bf16_t, float, float><<<gg, bb, 0, stream>>>(ctx, w_o, b_o, out, 1);
}

// Round 3
// 642.934 us; speedup vs baseline: 1.1595x; 1.1595x over previous
//
#include <hip/hip_runtime.h>
#include <hip/hip_bf16.h>

// MultiHeadAttentionBlock: B=2, S=4096, D=512, H=8, DK=64.
// fp32 in/out, bf16 MFMA compute, fp32 accumulation.
// Pipeline: cvt weights->bf16; 3x proj GEMM (Q,K head-split; V transposed);
// flash attention (KV=64, per-wave LDS, no block barriers); out proj.

typedef __bf16 bf16_t;
typedef __bf16 bf16x8 __attribute__((ext_vector_type(8)));
typedef __bf16 bf16x4 __attribute__((ext_vector_type(4)));
typedef float f32x4 __attribute__((ext_vector_type(4)));

#define S_LEN 4096
#define NH 8
#define DK 64
#define DMODEL 512
#define NB 2

__device__ inline bf16x8 frag8(const bf16_t* p) {
  return *reinterpret_cast<const bf16x8*>(p);
}
__device__ inline bf16x8 frag8(const float* p) {
  f32x4 a = *reinterpret_cast<const f32x4*>(p);
  f32x4 b = *reinterpret_cast<const f32x4*>(p + 4);
  bf16x8 r;
#pragma unroll
  for (int j = 0; j < 4; ++j) { r[j] = (__bf16)a[j]; r[j + 4] = (__bf16)b[j]; }
  return r;
}

// ---------------------------------------------------------------------------
// One-time fp32 -> bf16 weight conversion. grid (256, 4), 4 elems/thread.
// ---------------------------------------------------------------------------
__global__ __launch_bounds__(256) void cvt_weights(
    const float* __restrict__ w0, const float* __restrict__ w1,
    const float* __restrict__ w2, const float* __restrict__ w3,
    bf16_t* __restrict__ o0, bf16_t* __restrict__ o1,
    bf16_t* __restrict__ o2, bf16_t* __restrict__ o3)
{
  const float* src = blockIdx.y == 0 ? w0 : blockIdx.y == 1 ? w1
                   : blockIdx.y == 2 ? w2 : w3;
  bf16_t* dst = blockIdx.y == 0 ? o0 : blockIdx.y == 1 ? o1
              : blockIdx.y == 2 ? o2 : o3;
  const int i = (blockIdx.x * 256 + threadIdx.x) * 4;
  f32x4 v = *reinterpret_cast<const f32x4*>(src + i);
  bf16x4 r;
#pragma unroll
  for (int j = 0; j < 4; ++j) r[j] = (__bf16)v[j];
  *reinterpret_cast<bf16x4*>(dst + i) = r;
}

// ---------------------------------------------------------------------------
// GEMM: out[m][n] = sum_k X[m][k] * W[n][k] + bias[n]
// M=8192, N=512, K=512. Tile 64x64/block, wave -> 16(m) x 64(n). W pre-cvt bf16.
// mode 0: out [B*H][S][DK]; mode 2: [B*H][DK][S] (V transposed); mode 1: [m][n].
// ---------------------------------------------------------------------------
template <typename TA, typename TO>
__global__ __launch_bounds__(256) void gemm_proj(
    const TA* __restrict__ X, const bf16_t* __restrict__ W,
    const float* __restrict__ bias, TO* __restrict__ out, int mode)
{
  const int mtile = blockIdx.x * 64;
  const int ntile = blockIdx.y * 64;
  const int wave = threadIdx.x >> 6;
  const int lane = threadIdx.x & 63;
  const int l16 = lane & 15;
  const int g = lane >> 4;
  const int m0 = mtile + wave * 16;

  f32x4 acc[4];
#pragma unroll
  for (int nb = 0; nb < 4; ++nb) acc[nb] = (f32x4){0.f, 0.f, 0.f, 0.f};

  const TA* xrow = X + (size_t)(m0 + l16) * DMODEL + g * 8;
  const bf16_t* wbase = W + (size_t)(ntile + l16) * DMODEL + g * 8;

#pragma unroll 4
  for (int k = 0; k < DMODEL; k += 32) {
    bf16x8 af = frag8(xrow + k);
#pragma unroll
    for (int nb = 0; nb < 4; ++nb) {
      bf16x8 bfr = frag8(wbase + (size_t)nb * 16 * DMODEL + k);
      acc[nb] = __builtin_amdgcn_mfma_f32_16x16x32_bf16(af, bfr, acc[nb], 0, 0, 0);
    }
  }

#pragma unroll
  for (int nb = 0; nb < 4; ++nb) {
    const int n = ntile + nb * 16 + l16;
    const float bv = bias[n];
#pragma unroll
    for (int r = 0; r < 4; ++r) {
      const int m = m0 + g * 4 + r;
      float vv = acc[nb][r] + bv;
      size_t addr;
      if (mode == 0) {            // head-split [b*H+h][s][dk]
        int b = m >> 12, s = m & (S_LEN - 1);
        int h = n >> 6, d = n & 63;
        addr = (((size_t)(b * NH + h) * S_LEN) + s) * DK + d;
      } else if (mode == 2) {     // V transposed [b*H+h][dk][s]
        int b = m >> 12, s = m & (S_LEN - 1);
        int h = n >> 6, d = n & 63;
        addr = (((size_t)(b * NH + h) * DK) + d) * S_LEN + s;
      } else {                    // plain [m][n]
        addr = (size_t)m * DMODEL + n;
      }
      out[addr] = (TO)vv;
    }
  }
}

// ---------------------------------------------------------------------------
// Flash attention. Grid: (S/64, B*H). Block 256 = 4 waves; each wave owns
// 16 q-rows, fully independent (per-wave P tile in LDS, NO block barriers —
// wave-internal DS ordering + compiler lgkmcnt handle the RAW).
// KV tile = 64. pshare rows padded to 72 elems (144B = 9*16B) so the PV
// ds_read_b128 spreads across bank slots (stride-64B was a 16-way conflict).
// ---------------------------------------------------------------------------
__global__ __launch_bounds__(256) void attn_kernel(
    const bf16_t* __restrict__ Qh, const bf16_t* __restrict__ Kh,
    const bf16_t* __restrict__ Vt, bf16_t* __restrict__ ctx)
{
  const int bh = blockIdx.y;                 // b*H + h
  const int b = bh >> 3, h = bh & 7;
  const int qbase = blockIdx.x * 64;
  const int wave = threadIdx.x >> 6;
  const int lane = threadIdx.x & 63;
  const int l16 = lane & 15;
  const int g = lane >> 4;                   // 0..3

  const bf16_t* Qp = Qh + (size_t)bh * S_LEN * DK;
  const bf16_t* Kp = Kh + (size_t)bh * S_LEN * DK;
  const bf16_t* Vp = Vt + (size_t)bh * DK * S_LEN;

  const int qrow0 = qbase + wave * 16;

  // Q fragments (2 k-steps of 32), pre-scaled by 1/sqrt(DK)=0.125 (exact)
  bf16x8 qf[2];
#pragma unroll
  for (int ks = 0; ks < 2; ++ks) {
    bf16x8 t = *reinterpret_cast<const bf16x8*>(
        Qp + (size_t)(qrow0 + l16) * DK + ks * 32 + g * 8);
#pragma unroll
    for (int j = 0; j < 8; ++j) t[j] = (__bf16)((float)t[j] * 0.125f);
    qf[ks] = t;
  }

  f32x4 o[4];
#pragma unroll
  for (int db = 0; db < 4; ++db) o[db] = (f32x4){0.f, 0.f, 0.f, 0.f};
  float m_run[4], l_run[4];
#pragma unroll
  for (int r = 0; r < 4; ++r) { m_run[r] = -1e30f; l_run[r] = 0.f; }

  __shared__ bf16_t pshare[4][16][72];       // per-wave P tile, padded rows

  for (int kv = 0; kv < S_LEN; kv += 64) {
    // ---- scores: 16 q-rows x 64 kv-cols (8 MFMA) ----
    f32x4 sc[4];
#pragma unroll
    for (int nb = 0; nb < 4; ++nb) {
      f32x4 a = (f32x4){0.f, 0.f, 0.f, 0.f};
#pragma unroll
      for (int ks = 0; ks < 2; ++ks) {
        bf16x8 kf = *reinterpret_cast<const bf16x8*>(
            Kp + (size_t)(kv + nb * 16 + l16) * DK + ks * 32 + g * 8);
        a = __builtin_amdgcn_mfma_f32_16x16x32_bf16(qf[ks], kf, a, 0, 0, 0);
      }
      sc[nb] = a;
    }

    // ---- online softmax (row = g*4+r; 16-lane-group reduction) ----
#pragma unroll
    for (int r = 0; r < 4; ++r) {
      float vmax = fmaxf(fmaxf(sc[0][r], sc[1][r]), fmaxf(sc[2][r], sc[3][r]));
      vmax = fmaxf(vmax, __shfl_xor(vmax, 1));
      vmax = fmaxf(vmax, __shfl_xor(vmax, 2));
      vmax = fmaxf(vmax, __shfl_xor(vmax, 4));
      vmax = fmaxf(vmax, __shfl_xor(vmax, 8));
      const float mnew = fmaxf(m_run[r], vmax);
      const float alpha = __expf(m_run[r] - mnew);
      float p[4], psum = 0.f;
#pragma unroll
      for (int nb = 0; nb < 4; ++nb) { p[nb] = __expf(sc[nb][r] - mnew); psum += p[nb]; }
      psum += __shfl_xor(psum, 1);
      psum += __shfl_xor(psum, 2);
      psum += __shfl_xor(psum, 4);
      psum += __shfl_xor(psum, 8);
      l_run[r] = l_run[r] * alpha + psum;
      m_run[r] = mnew;
#pragma unroll
      for (int db = 0; db < 4; ++db) o[db][r] *= alpha;
      const int row = g * 4 + r;
#pragma unroll
      for (int nb = 0; nb < 4; ++nb)
        pshare[wave][row][nb * 16 + l16] = (__bf16)p[nb];
    }
    // no __syncthreads: pshare is per-wave; ds ops execute in order per wave.

    // ---- PV: P (16x64) x V^T (64d x 64kv), 8 MFMA ----
#pragma unroll
    for (int ks = 0; ks < 2; ++ks) {
      bf16x8 pf = *reinterpret_cast<const bf16x8*>(
          &pshare[wave][l16][ks * 32 + g * 8]);
#pragma unroll
      for (int db = 0; db < 4; ++db) {
        bf16x8 vf = *reinterpret_cast<const bf16x8*>(
            Vp + (size_t)(db * 16 + l16) * S_LEN + kv + ks * 32 + g * 8);
        o[db] = __builtin_amdgcn_mfma_f32_16x16x32_bf16(pf, vf, o[db], 0, 0, 0);
      }
    }
  }

  // ---- epilogue: O / l -> ctx[b][s][h*64+d] (plain [m][512] for out-proj) ----
#pragma unroll
  for (int db = 0; db < 4; ++db) {
#pragma unroll
    for (int r = 0; r < 4; ++r) {
      const int row = qrow0 + g * 4 + r;
      const int col = db * 16 + l16;
      const float vv = o[db][r] / l_run[r];
      ctx[(((size_t)(b * S_LEN + row)) * NH + h) * DK + col] = (bf16_t)vv;
    }
  }
}

// ---------------------------------------------------------------------------
extern "C" void kernel_launch(void* const* d_in, const int* in_sizes, int n_in,
                              void* d_out, int out_size, void* d_ws, size_t ws_size,
                              hipStream_t stream)
{
  const float* q   = (const float*)d_in[0];
  const float* k   = (const float*)d_in[1];
  const float* v   = (const float*)d_in[2];
  const float* w_q = (const float*)d_in[3];
  const float* b_q = (const float*)d_in[4];
  const float* w_k = (const float*)d_in[5];
  const float* b_k = (const float*)d_in[6];
  const float* w_v = (const float*)d_in[7];
  const float* b_v = (const float*)d_in[8];
  const float* w_o = (const float*)d_in[9];
  const float* b_o = (const float*)d_in[10];
  float* out = (float*)d_out;

  char* ws = (char*)d_ws;
  const size_t sz = (size_t)NB * NH * S_LEN * DK * sizeof(bf16_t);  // 8 MiB each
  const size_t wsz = (size_t)DMODEL * DMODEL * sizeof(bf16_t);      // 512 KiB each
  bf16_t* Qh  = (bf16_t*)(ws);
  bf16_t* Kh  = (bf16_t*)(ws + sz);
  bf16_t* Vt  = (bf16_t*)(ws + 2 * sz);
  bf16_t* ctx = (bf16_t*)(ws + 3 * sz);
  bf16_t* Wq  = (bf16_t*)(ws + 4 * sz);
  bf16_t* Wk  = (bf16_t*)(ws + 4 * sz + wsz);
  bf16_t* Wv  = (bf16_t*)(ws + 4 * sz + 2 * wsz);
  bf16_t* Wo  = (bf16_t*)(ws + 4 * sz + 3 * wsz);

  cvt_weights<<<dim3(256, 4), 256, 0, stream>>>(w_q, w_k, w_v, w_o, Wq, Wk, Wv, Wo);

  dim3 gg(128, 8), bb(256);
  gemm_proj<float, bf16_t><<<gg, bb, 0, stream>>>(q, Wq, b_q, Qh, 0);
  gemm_proj<float, bf16_t><<<gg, bb, 0, stream>>>(k, Wk, b_k, Kh, 0);
  gemm_proj<float, bf16_t><<<gg, bb, 0, stream>>>(v, Wv, b_v, Vt, 2);
  attn_kernel<<<dim3(S_LEN / 64, NB * NH), bb, 0, stream>>>(Qh, Kh, Vt, ctx);
  gemm_proj<bf16_t, float><<<gg, bb, 0, stream>>>(ctx, Wo, b_o, out, 1);
}